// Round 13
// baseline (754.462 us; speedup 1.0000x reference)
//
#include <hip/hip_runtime.h>

// GCN 2-layer. R13: zero fine-grained-random global access.
//  - coarse 8-chunk dst partition (LDS-staged, coalesced writes) replaces the
//    fine counting sort (R11/R12: random 4B/2B scatter was request-bound).
//  - aggregation gathers from LDS-resident column slices (100KB/block:
//    2 cols x 20000 fp16 interleaved + fp32 acc[2500][2]) via ds_add_f32;
//    pair stream is coalesced. Random L2 line-requests eliminated.
//  - g1/h1p/g2 stored column-major (NPAD=20032 rows); gemm2 re-transposes
//    its A tile through a padded LDS stage.
// p1: LDS hist -> ghist u8 + bucket counts (+WT transpose blocks)
// p2: ghist column-reduce -> cnt; block 79 scans bucket counts -> gpos/base
// p3: coarse partition (+gemm1 MFMA -> g1T)
// agg1 (512 blk) -> h1pT; mgemm2 (313 blk) -> g2T; agg2 (256 blk) -> out.

#define N_NODES 20000
#define N_EDGES 640000
#define OUT_DIM 64
#define NPAD 20032
#define NCHUNK 8
#define CHUNK 2500
#define HB 256
#define EPB (N_EDGES / HB)            // 2500
#define WT_NB ((128 * 128 + 64 * 128) / 256)  // 96

typedef _Float16 half4_t __attribute__((ext_vector_type(4)));
typedef _Float16 half8_t __attribute__((ext_vector_type(8)));
typedef float float4_t __attribute__((ext_vector_type(4)));

__device__ inline float h2f(unsigned int u) {
    return (float)__builtin_bit_cast(_Float16, (unsigned short)u);
}
__device__ inline unsigned short f2h(float f) {
    return __builtin_bit_cast(unsigned short, (_Float16)f);
}

// p1: blocks [0,HB): LDS histogram of dst chunk -> ghist u8 + per-bucket
// counts gbcnt[b][8]; blocks [HB,..): WT transpose/cast.
__global__ __launch_bounds__(256) void k_p1(const int* __restrict__ dst,
                                            unsigned char* __restrict__ ghist,
                                            int* __restrict__ gbcnt,
                                            const float* __restrict__ W1,
                                            const float* __restrict__ W2,
                                            _Float16* __restrict__ WT1,
                                            _Float16* __restrict__ WT2) {
    __shared__ unsigned int hist[N_NODES];
    __shared__ int lbcnt[NCHUNK];
    const int b = blockIdx.x, tid = threadIdx.x;
    if (b < HB) {
        for (int i = tid; i < N_NODES; i += 256) hist[i] = 0;
        if (tid < NCHUNK) lbcnt[tid] = 0;
        __syncthreads();
        const int base = b * EPB;
        for (int i = tid; i < EPB; i += 256) {
            int d = dst[base + i];
            atomicAdd(&hist[d], 1u);
            atomicAdd(&lbcnt[d / CHUNK], 1);
        }
        __syncthreads();
        unsigned int* gh32 = (unsigned int*)(ghist + (size_t)b * N_NODES);
        for (int i = tid; i < N_NODES / 4; i += 256) {
            unsigned int v = (hist[4 * i] & 0xff) | ((hist[4 * i + 1] & 0xff) << 8) |
                             ((hist[4 * i + 2] & 0xff) << 16) | ((hist[4 * i + 3] & 0xff) << 24);
            gh32[i] = v;
        }
        if (tid < NCHUNK) gbcnt[b * NCHUNK + tid] = lbcnt[tid];
    } else {
        int i = (b - HB) * 256 + tid;
        if (i < 128 * 128) {
            int c = i >> 7, k = i & 127;
            WT1[i] = (_Float16)W1[k * 128 + c];
        } else {
            int o = i - 128 * 128;
            int c = o >> 7, k = o & 127;
            WT2[o] = (_Float16)W2[k * 64 + c];
        }
    }
}

// p2: blocks [0,79): per-node reduce of ghist -> cnt. Block 79: scan
// gbcnt[256][8] -> gpos (global start per (block,bucket)) + bucketBase[9].
__global__ __launch_bounds__(256) void k_p2(const unsigned char* __restrict__ ghist,
                                            int* __restrict__ cnt,
                                            const int* __restrict__ gbcnt,
                                            int* __restrict__ gpos,
                                            int* __restrict__ bucketBase) {
    const int tid = threadIdx.x;
    if (blockIdx.x < 79) {
        int n = blockIdx.x * 256 + tid;
        if (n >= N_NODES) return;
        unsigned int acc = 0;
#pragma unroll 8
        for (int b = 0; b < HB; ++b) acc += ghist[(size_t)b * N_NODES + n];
        cnt[n] = (int)acc;
        return;
    }
    // scan block
    __shared__ int wsum[4];
    __shared__ int stot;
    const int lane = tid & 63, wv = tid >> 6;
    int basek = 0;
    for (int k = 0; k < NCHUNK; ++k) {
        int v = gbcnt[tid * NCHUNK + k];
        int inc = v;
        for (int off = 1; off < 64; off <<= 1) {
            int u = __shfl_up(inc, off, 64);
            if (lane >= off) inc += u;
        }
        if (lane == 63) wsum[wv] = inc;
        __syncthreads();
        int add = 0;
        for (int w = 0; w < 4; ++w)
            if (w < wv) add += wsum[w];
        gpos[tid * NCHUNK + k] = basek + add + inc - v;
        if (tid == 255) stot = add + inc;
        if (tid == 0) bucketBase[k] = basek;
        __syncthreads();
        basek += stot;
        __syncthreads();
    }
    if (tid == 0) bucketBase[NCHUNK] = N_EDGES;
}

// p3: blocks [0,HB): coarse partition -- stage pairs {src | dst_local<<16}
// per bucket in LDS, copy out coalesced. Blocks [HB,..): gemm1 MFMA
// g1T[col][row] = rsqrt(cnt+1)[row] * (x @ W1), fp16 column-major.
__global__ __launch_bounds__(256) void k_p3(const int* __restrict__ src,
                                            const int* __restrict__ dst,
                                            const int* __restrict__ gbcnt,
                                            const int* __restrict__ gpos,
                                            unsigned int* __restrict__ gpairs,
                                            const float* __restrict__ A,
                                            const _Float16* __restrict__ WT,
                                            const int* __restrict__ cnt,
                                            unsigned short* __restrict__ g1T) {
    __shared__ unsigned int prs[EPB];
    __shared__ int lcnt[NCHUNK], lboff[NCHUNK];
    const int b = blockIdx.x, tid = threadIdx.x;
    if (b < HB) {
        if (tid < NCHUNK) lcnt[tid] = 0;
        if (tid == 0) {
            int a = 0;
            for (int k = 0; k < NCHUNK; ++k) { lboff[k] = a; a += gbcnt[b * NCHUNK + k]; }
        }
        __syncthreads();
        for (int i = tid; i < EPB; i += 256) {
            int e = b * EPB + i;
            int s = src[e], d = dst[e];
            int k = d / CHUNK;
            int dl = d - k * CHUNK;
            int r = atomicAdd(&lcnt[k], 1);
            prs[lboff[k] + r] = (unsigned int)s | ((unsigned int)dl << 16);
        }
        __syncthreads();
        for (int k = 0; k < NCHUNK; ++k) {
            int n = lcnt[k];
            int gp = gpos[b * NCHUNK + k];
            int lo = lboff[k];
            for (int i = tid; i < n; i += 256) gpairs[gp + i] = prs[lo + i];
        }
        return;
    }
    // ---- gemm1 ----
    const int wave = tid >> 6;
    const int lane = tid & 63;
    const int task = (b - HB) * 4 + wave;
    if (task >= 2 * (N_NODES / 16)) return;
    const int strip = task >> 1;
    const int nh = task & 1;
    const int row0 = strip * 16;
    const int mrow = row0 + (lane & 15);
    const int kq = (lane >> 4) * 8;

    half8_t af[4];
#pragma unroll
    for (int kc = 0; kc < 4; ++kc) {
        const float* ap = A + (size_t)mrow * 128 + kc * 32 + kq;
        float4_t f0 = *(const float4_t*)ap;
        float4_t f1 = *(const float4_t*)(ap + 4);
        half8_t h;
        h[0] = (_Float16)f0[0]; h[1] = (_Float16)f0[1];
        h[2] = (_Float16)f0[2]; h[3] = (_Float16)f0[3];
        h[4] = (_Float16)f1[0]; h[5] = (_Float16)f1[1];
        h[6] = (_Float16)f1[2]; h[7] = (_Float16)f1[3];
        af[kc] = h;
    }

    float4_t acc[4];
#pragma unroll
    for (int nt = 0; nt < 4; ++nt) acc[nt] = (float4_t)(0.0f);
#pragma unroll
    for (int nt = 0; nt < 4; ++nt) {
        const _Float16* wp = WT + (size_t)((nh * 4 + nt) * 16 + (lane & 15)) * 128 + kq;
#pragma unroll
        for (int kc = 0; kc < 4; ++kc) {
            half8_t bf = *(const half8_t*)(wp + kc * 32);
            acc[nt] = __builtin_amdgcn_mfma_f32_16x16x32_f16(af[kc], bf, acc[nt], 0, 0, 0);
        }
    }
    const int rowb = row0 + (lane >> 4) * 4;
    float dvv[4];
#pragma unroll
    for (int r = 0; r < 4; ++r) dvv[r] = rsqrtf((float)cnt[rowb + r] + 1.0f);
#pragma unroll
    for (int nt = 0; nt < 4; ++nt) {
        int col = (nh * 4 + nt) * 16 + (lane & 15);
        half4_t h;
#pragma unroll
        for (int r = 0; r < 4; ++r) h[r] = (_Float16)(dvv[r] * acc[nt][r]);
        *(half4_t*)((_Float16*)g1T + (size_t)col * NPAD + rowb) = h;
    }
}

// agg1: block = (2-col slice, chunk). LDS: interleaved slice u32[20000]
// (100KB total w/ acc). Gather from LDS, ds_add_f32 accumulate, epilogue
// relu(acc*dinv + b1) -> h1pT fp16 column-major.
__global__ __launch_bounds__(256) void k_agg1(const unsigned int* __restrict__ gpairs,
                                              const int* __restrict__ bucketBase,
                                              const unsigned short* __restrict__ g1T,
                                              const int* __restrict__ cnt,
                                              const float* __restrict__ b1,
                                              unsigned short* __restrict__ h1pT) {
    __shared__ unsigned int sl[N_NODES];
    __shared__ float accf[CHUNK * 2];
    const int tid = threadIdx.x;
    const int slice = blockIdx.x >> 3;     // 0..63
    const int chunk = blockIdx.x & 7;
    const int c0 = slice * 2;

    const unsigned int* colA = (const unsigned int*)(g1T + (size_t)c0 * NPAD);
    const unsigned int* colB = (const unsigned int*)(g1T + (size_t)(c0 + 1) * NPAD);
    for (int j = tid; j < N_NODES / 2; j += 256) {
        unsigned int va = colA[j], vb = colB[j];
        sl[2 * j]     = (va & 0xffffu) | (vb << 16);
        sl[2 * j + 1] = (va >> 16) | (vb & 0xffff0000u);
    }
    __syncthreads();
    const int d0 = chunk * CHUNK;
    for (int d = tid; d < CHUNK; d += 256) {       // self-loop init
        unsigned int sv = sl[d0 + d];
        accf[2 * d]     = h2f(sv & 0xffffu);
        accf[2 * d + 1] = h2f(sv >> 16);
    }
    __syncthreads();
    const int base = bucketBase[chunk];
    const int nk = bucketBase[chunk + 1] - base;
    for (int i = tid; i < nk; i += 256) {
        unsigned int p = gpairs[base + i];
        int s = p & 0xffffu;
        int dl = p >> 16;
        unsigned int sv = sl[s];
        atomicAdd(&accf[2 * dl], h2f(sv & 0xffffu));
        atomicAdd(&accf[2 * dl + 1], h2f(sv >> 16));
    }
    __syncthreads();
    const float bb0 = b1[c0], bb1 = b1[c0 + 1];
    for (int d = tid; d < CHUNK; d += 256) {
        int dg = d0 + d;
        float dv = rsqrtf((float)cnt[dg] + 1.0f);
        h1pT[(size_t)c0 * NPAD + dg]       = f2h(fmaxf(accf[2 * d] * dv + bb0, 0.0f));
        h1pT[(size_t)(c0 + 1) * NPAD + dg] = f2h(fmaxf(accf[2 * d + 1] * dv + bb1, 0.0f));
    }
}

// gemm2: A = h1pT (column-major) staged+transposed through padded LDS;
// g2T[col][row] = rsqrt(cnt+1)[row] * (h1p @ W2), fp16 column-major.
__global__ __launch_bounds__(256) void k_mgemm2(const unsigned short* __restrict__ h1pT,
                                                const _Float16* __restrict__ WT,
                                                const int* __restrict__ cnt,
                                                unsigned short* __restrict__ g2T) {
    __shared__ unsigned short at[4][16][136];   // +8 pad breaks frag-read conflicts
    const int tid = threadIdx.x, wv = tid >> 6, lane = tid & 63;
    const int R0 = blockIdx.x * 64;
#pragma unroll
    for (int it = 0; it < 16; ++it) {
        int idx = it * 256 + tid;       // 4096 u32 = 64 rows x 128 cols
        int j = idx & 31;               // row-pair within 64-row band
        int c = idx >> 5;               // col
        unsigned int v = *(const unsigned int*)(h1pT + (size_t)c * NPAD + R0 + 2 * j);
        int st = j >> 3, lr = (2 * j) & 15;
        at[st][lr][c]     = (unsigned short)(v & 0xffffu);
        at[st][lr + 1][c] = (unsigned short)(v >> 16);
    }
    __syncthreads();
    const int strip = blockIdx.x * 4 + wv;
    if (strip >= N_NODES / 16) return;
    const int kq = (lane >> 4) * 8;

    half8_t af[4];
#pragma unroll
    for (int kc = 0; kc < 4; ++kc)
        af[kc] = *(const half8_t*)&at[wv][lane & 15][kq + kc * 32];

    float4_t acc[4];
#pragma unroll
    for (int nt = 0; nt < 4; ++nt) acc[nt] = (float4_t)(0.0f);
#pragma unroll
    for (int nt = 0; nt < 4; ++nt) {
        const _Float16* wp = WT + (size_t)(nt * 16 + (lane & 15)) * 128 + kq;
#pragma unroll
        for (int kc = 0; kc < 4; ++kc) {
            half8_t bf = *(const half8_t*)(wp + kc * 32);
            acc[nt] = __builtin_amdgcn_mfma_f32_16x16x32_f16(af[kc], bf, acc[nt], 0, 0, 0);
        }
    }
    const int rowb = strip * 16 + (lane >> 4) * 4;
    float dvv[4];
#pragma unroll
    for (int r = 0; r < 4; ++r) dvv[r] = rsqrtf((float)cnt[rowb + r] + 1.0f);
#pragma unroll
    for (int nt = 0; nt < 4; ++nt) {
        int col = nt * 16 + (lane & 15);
        half4_t h;
#pragma unroll
        for (int r = 0; r < 4; ++r) h[r] = (_Float16)(dvv[r] * acc[nt][r]);
        *(half4_t*)((_Float16*)g2T + (size_t)col * NPAD + rowb) = h;
    }
}

// agg2: same LDS-gather structure on g2T (32 slices x 8 chunks); epilogue
// acc*dinv + b2 -> out fp32 row-major (float2 per dst).
__global__ __launch_bounds__(256) void k_agg2(const unsigned int* __restrict__ gpairs,
                                              const int* __restrict__ bucketBase,
                                              const unsigned short* __restrict__ g2T,
                                              const int* __restrict__ cnt,
                                              const float* __restrict__ b2,
                                              float* __restrict__ out) {
    __shared__ unsigned int sl[N_NODES];
    __shared__ float accf[CHUNK * 2];
    const int tid = threadIdx.x;
    const int slice = blockIdx.x >> 3;     // 0..31
    const int chunk = blockIdx.x & 7;
    const int c0 = slice * 2;

    const unsigned int* colA = (const unsigned int*)(g2T + (size_t)c0 * NPAD);
    const unsigned int* colB = (const unsigned int*)(g2T + (size_t)(c0 + 1) * NPAD);
    for (int j = tid; j < N_NODES / 2; j += 256) {
        unsigned int va = colA[j], vb = colB[j];
        sl[2 * j]     = (va & 0xffffu) | (vb << 16);
        sl[2 * j + 1] = (va >> 16) | (vb & 0xffff0000u);
    }
    __syncthreads();
    const int d0 = chunk * CHUNK;
    for (int d = tid; d < CHUNK; d += 256) {
        unsigned int sv = sl[d0 + d];
        accf[2 * d]     = h2f(sv & 0xffffu);
        accf[2 * d + 1] = h2f(sv >> 16);
    }
    __syncthreads();
    const int base = bucketBase[chunk];
    const int nk = bucketBase[chunk + 1] - base;
    for (int i = tid; i < nk; i += 256) {
        unsigned int p = gpairs[base + i];
        int s = p & 0xffffu;
        int dl = p >> 16;
        unsigned int sv = sl[s];
        atomicAdd(&accf[2 * dl], h2f(sv & 0xffffu));
        atomicAdd(&accf[2 * dl + 1], h2f(sv >> 16));
    }
    __syncthreads();
    const float bb0 = b2[c0], bb1 = b2[c0 + 1];
    for (int d = tid; d < CHUNK; d += 256) {
        int dg = d0 + d;
        float dv = rsqrtf((float)cnt[dg] + 1.0f);
        float2 o;
        o.x = accf[2 * d] * dv + bb0;
        o.y = accf[2 * d + 1] * dv + bb1;
        *(float2*)(out + (size_t)dg * OUT_DIM + c0) = o;
    }
}

extern "C" void kernel_launch(void* const* d_in, const int* in_sizes, int n_in,
                              void* d_out, int out_size, void* d_ws, size_t ws_size,
                              hipStream_t stream) {
    const float* x  = (const float*)d_in[0];
    const int*   ei = (const int*)d_in[1];
    const float* W1 = (const float*)d_in[2];
    const float* b1 = (const float*)d_in[3];
    const float* W2 = (const float*)d_in[4];
    const float* b2 = (const float*)d_in[5];

    const int* src = ei;
    const int* dst = ei + N_EDGES;

    char* w = (char*)d_ws;
    unsigned int*   gpairs = (unsigned int*)w;   w += sizeof(unsigned int) * N_EDGES;
    unsigned short* g1T    = (unsigned short*)w; w += sizeof(unsigned short) * (size_t)128 * NPAD;
    unsigned short* h1pT   = (unsigned short*)w; w += sizeof(unsigned short) * (size_t)128 * NPAD;
    unsigned short* g2T    = (unsigned short*)w; w += sizeof(unsigned short) * (size_t)64 * NPAD;
    _Float16*       WT1    = (_Float16*)w;       w += sizeof(_Float16) * 128 * 128;
    _Float16*       WT2    = (_Float16*)w;       w += sizeof(_Float16) * 64 * 128;
    int*            cnt    = (int*)w;            w += sizeof(int) * N_NODES;
    int*            gbcnt  = (int*)w;            w += sizeof(int) * HB * NCHUNK;
    int*            gpos   = (int*)w;            w += sizeof(int) * HB * NCHUNK;
    int*            bucketBase = (int*)w;        w += sizeof(int) * 16;
    unsigned char*  ghist  = (unsigned char*)w;  w += (size_t)HB * N_NODES;
    float*          out    = (float*)d_out;

    k_p1<<<HB + WT_NB, 256, 0, stream>>>(dst, ghist, gbcnt, W1, W2, WT1, WT2);
    k_p2<<<80, 256, 0, stream>>>(ghist, cnt, gbcnt, gpos, bucketBase);
    k_p3<<<HB + (2 * (N_NODES / 16) + 3) / 4, 256, 0, stream>>>(
        src, dst, gbcnt, gpos, gpairs, x, WT1, cnt, g1T);

    k_agg1<<<64 * NCHUNK, 256, 0, stream>>>(gpairs, bucketBase, g1T, cnt, b1, h1pT);
    k_mgemm2<<<(N_NODES + 63) / 64, 256, 0, stream>>>(h1pT, WT2, cnt, g2T);
    k_agg2<<<32 * NCHUNK, 256, 0, stream>>>(gpairs, bucketBase, g2T, cnt, b2, out);
}

// Round 14
// 166.663 us; speedup vs baseline: 4.5269x; 4.5269x over previous
//
#include <hip/hip_runtime.h>

// GCN 2-layer. R14 = revert to R12 (best, 165.3us). R13's LDS-gather agg
// regressed 4.6x: 123M serialized bank-conflicted LDS ops (3.5M conflicts
// measured) + 1 block/CU occupancy vs R12's 3.8M L2 line requests.
// R12: u16 scatter table (3.2MB < 4MB per-XCD L2), no-global-atomic LDS
// counting-sort build (p1 hist -> p2 prefix -> p3 scatter+gemm1),
// MFMA 16x16x32_f16 GEMMs, L2-blocked column-half aggs with half8 gathers.

#define N_NODES 20000
#define N_EDGES 640000
#define IN_DIM 128
#define HID_DIM 128
#define OUT_DIM 64

#define STRIDE 80
#define HB 256                       // histogram blocks
#define EPB (N_EDGES / HB)           // 2500 edges per histogram block
#define WT_NB ((128 * 128 + 64 * 128) / 256)  // 96 (exact)
#define GEMM1_NB ((2 * (N_NODES / 16) + 3) / 4)  // 625

typedef _Float16 half8_t __attribute__((ext_vector_type(8)));
typedef float float4_t __attribute__((ext_vector_type(4)));

// p1: blocks [0,HB) LDS-histogram their 2500-edge chunk -> ghist (u8, packed
// u32 writes); blocks [HB, HB+WT_NB) transpose+cast W1/W2 -> fp16 WT[col][k].
__global__ __launch_bounds__(256) void k_p1(const int* __restrict__ dst,
                                            unsigned char* __restrict__ ghist,
                                            const float* __restrict__ W1,
                                            const float* __restrict__ W2,
                                            _Float16* __restrict__ WT1,
                                            _Float16* __restrict__ WT2) {
    __shared__ unsigned int hist[N_NODES];
    const int b = blockIdx.x, tid = threadIdx.x;
    if (b < HB) {
        for (int i = tid; i < N_NODES; i += 256) hist[i] = 0;
        __syncthreads();
        const int base = b * EPB;
        for (int i = tid; i < EPB; i += 256)
            atomicAdd(&hist[dst[base + i]], 1u);
        __syncthreads();
        unsigned int* gh32 = (unsigned int*)(ghist + (size_t)b * N_NODES);
        for (int i = tid; i < N_NODES / 4; i += 256) {
            unsigned int v = (hist[4 * i] & 0xff) | ((hist[4 * i + 1] & 0xff) << 8) |
                             ((hist[4 * i + 2] & 0xff) << 16) | ((hist[4 * i + 3] & 0xff) << 24);
            gh32[i] = v;
        }
    } else {
        int i = (b - HB) * 256 + tid;
        if (i < 128 * 128) {
            int c = i >> 7, k = i & 127;
            WT1[i] = (_Float16)W1[k * 128 + c];
        } else {
            int o = i - 128 * 128;
            int c = o >> 7, k = o & 127;
            WT2[o] = (_Float16)W2[k * 64 + c];
        }
    }
}

// p2: thread per node: exclusive prefix over the HB block counts -> boff u8,
// total -> cnt. Coalesced u8 column walk; unroll for outstanding loads.
__global__ __launch_bounds__(256) void k_p2(const unsigned char* __restrict__ ghist,
                                            unsigned char* __restrict__ boff,
                                            int* __restrict__ cnt) {
    int n = blockIdx.x * 256 + threadIdx.x;
    if (n >= N_NODES) return;
    unsigned int acc = 0;
#pragma unroll 8
    for (int b = 0; b < HB; ++b) {
        size_t idx = (size_t)b * N_NODES + n;
        unsigned int v = ghist[idx];
        boff[idx] = (unsigned char)acc;
        acc += v;
    }
    cnt[n] = (int)acc;
}

// p3: blocks [0,HB) scatter their edges via LDS rank + boff into u16 padded
// buckets (3.2MB -> L2-resident per XCD); blocks [HB, ...) run gemm1
// (g = rsqrt(cnt+1)*(x@W1), MFMA f16, column-blocked GA/GB).
__global__ __launch_bounds__(256) void k_p3(const int* __restrict__ src,
                                            const int* __restrict__ dst,
                                            const unsigned char* __restrict__ boff,
                                            unsigned short* __restrict__ esrc_pad,
                                            const float* __restrict__ A,
                                            const _Float16* __restrict__ WT,
                                            const int* __restrict__ cnt,
                                            _Float16* __restrict__ GA,
                                            _Float16* __restrict__ GB) {
    __shared__ unsigned int hist[N_NODES];
    const int b = blockIdx.x, tid = threadIdx.x;
    if (b < HB) {
        for (int i = tid; i < N_NODES; i += 256) hist[i] = 0;
        __syncthreads();
        const int base = b * EPB;
        const unsigned char* bo = boff + (size_t)b * N_NODES;
        for (int i = tid; i < EPB; i += 256) {
            int e = base + i;
            int s = src[e], d = dst[e];
            unsigned int rank = atomicAdd(&hist[d], 1u);
            int pos = (int)bo[d] + (int)rank;
            if (pos < STRIDE) esrc_pad[d * STRIDE + pos] = (unsigned short)s;
        }
        return;
    }
    // ---- gemm1 blocks ----
    const int wave = tid >> 6;
    const int lane = tid & 63;
    const int task = (b - HB) * 4 + wave;
    if (task >= 2 * (N_NODES / 16)) return;
    const int strip = task >> 1;
    const int nh = task & 1;
    const int row0 = strip * 16;
    const int mrow = row0 + (lane & 15);
    const int kq = (lane >> 4) * 8;
    _Float16* G = nh ? GB : GA;

    half8_t af[4];
#pragma unroll
    for (int kc = 0; kc < 4; ++kc) {
        const float* ap = A + (size_t)mrow * 128 + kc * 32 + kq;
        float4_t f0 = *(const float4_t*)ap;
        float4_t f1 = *(const float4_t*)(ap + 4);
        half8_t h;
        h[0] = (_Float16)f0[0]; h[1] = (_Float16)f0[1];
        h[2] = (_Float16)f0[2]; h[3] = (_Float16)f0[3];
        h[4] = (_Float16)f1[0]; h[5] = (_Float16)f1[1];
        h[6] = (_Float16)f1[2]; h[7] = (_Float16)f1[3];
        af[kc] = h;
    }

    float4_t acc[4];
#pragma unroll
    for (int nt = 0; nt < 4; ++nt) acc[nt] = (float4_t)(0.0f);
#pragma unroll
    for (int nt = 0; nt < 4; ++nt) {
        const _Float16* wp = WT + (size_t)((nh * 4 + nt) * 16 + (lane & 15)) * 128 + kq;
#pragma unroll
        for (int kc = 0; kc < 4; ++kc) {
            half8_t bf = *(const half8_t*)(wp + kc * 32);
            acc[nt] = __builtin_amdgcn_mfma_f32_16x16x32_f16(af[kc], bf, acc[nt], 0, 0, 0);
        }
    }
#pragma unroll
    for (int r = 0; r < 4; ++r) {
        int row = row0 + (lane >> 4) * 4 + r;
        float dv = rsqrtf((float)cnt[row] + 1.0f);
#pragma unroll
        for (int nt = 0; nt < 4; ++nt)
            G[(size_t)row * 64 + nt * 16 + (lane & 15)] = (_Float16)(dv * acc[nt][r]);
    }
}

// GEMM2: g2 = rsqrt(cnt+1) * (h1p @ W2), A fp16 direct, out fp16.
__global__ __launch_bounds__(256) void k_mgemm2(const _Float16* __restrict__ A,
                                                const _Float16* __restrict__ WT,
                                                const int* __restrict__ cnt,
                                                _Float16* __restrict__ G) {
    const int wave = threadIdx.x >> 6;
    const int lane = threadIdx.x & 63;
    const int task = blockIdx.x * 4 + wave;
    if (task >= 2 * (N_NODES / 16)) return;
    const int strip = task >> 1;
    const int nh = task & 1;
    const int row0 = strip * 16;
    const int mrow = row0 + (lane & 15);
    const int kq = (lane >> 4) * 8;

    half8_t af[4];
#pragma unroll
    for (int kc = 0; kc < 4; ++kc)
        af[kc] = *(const half8_t*)(A + (size_t)mrow * 128 + kc * 32 + kq);

    float4_t acc[2];
#pragma unroll
    for (int nt = 0; nt < 2; ++nt) acc[nt] = (float4_t)(0.0f);
#pragma unroll
    for (int nt = 0; nt < 2; ++nt) {
        const _Float16* wp = WT + (size_t)((nh * 2 + nt) * 16 + (lane & 15)) * 128 + kq;
#pragma unroll
        for (int kc = 0; kc < 4; ++kc) {
            half8_t bf = *(const half8_t*)(wp + kc * 32);
            acc[nt] = __builtin_amdgcn_mfma_f32_16x16x32_f16(af[kc], bf, acc[nt], 0, 0, 0);
        }
    }
#pragma unroll
    for (int r = 0; r < 4; ++r) {
        int row = row0 + (lane >> 4) * 4 + r;
        float dv = rsqrtf((float)cnt[row] + 1.0f);
#pragma unroll
        for (int nt = 0; nt < 2; ++nt)
            G[(size_t)row * 64 + (nh * 2 + nt) * 16 + (lane & 15)] =
                (_Float16)(dv * acc[nt][r]);
    }
}

// agg128 half-pass: gathers 64-col rows (128B) from G (2.56MB, L2-resident),
// one wave/node, 8 edges/iter. Writes h1p cols [COL0,COL0+64) biased+relu'd.
template <int COL0>
__global__ __launch_bounds__(256) void k_agg128h(const int* __restrict__ cnt,
                                                 const unsigned short* __restrict__ esrc_pad,
                                                 const _Float16* __restrict__ G,
                                                 const float* __restrict__ bias,
                                                 _Float16* __restrict__ out) {
    const int wave = threadIdx.x >> 6;
    const int lane = threadIdx.x & 63;
    const int node = blockIdx.x * 4 + wave;
    if (node >= N_NODES) return;
    const int eidx = lane >> 3;
    const int flane = lane & 7;

    const int end = cnt[node];
    const int base = node * STRIDE;

    float acc[8];
#pragma unroll
    for (int p = 0; p < 8; ++p) acc[p] = 0.0f;
    if (lane < 8) {
        half8_t s = *(const half8_t*)(G + (size_t)node * 64 + flane * 8);
#pragma unroll
        for (int p = 0; p < 8; ++p) acc[p] = (float)s[p];
    }

    int j = 0;
    for (; j + 7 < end; j += 8) {
        int s = (int)esrc_pad[base + j + eidx];
        half8_t r = *(const half8_t*)(G + (size_t)s * 64 + flane * 8);
#pragma unroll
        for (int p = 0; p < 8; ++p) acc[p] += (float)r[p];
    }
    if (j < end) {
        int idx = j + eidx;
        int s = (int)esrc_pad[base + ((idx < end) ? idx : (end - 1))];
        float valid = (idx < end) ? 1.0f : 0.0f;
        half8_t r = *(const half8_t*)(G + (size_t)s * 64 + flane * 8);
#pragma unroll
        for (int p = 0; p < 8; ++p) acc[p] += valid * (float)r[p];
    }

#pragma unroll
    for (int p = 0; p < 8; ++p) {
        acc[p] += __shfl_xor(acc[p], 32, 64);
        acc[p] += __shfl_xor(acc[p], 16, 64);
        acc[p] += __shfl_xor(acc[p], 8, 64);
    }

    if (lane < 8) {
        float dv = rsqrtf((float)end + 1.0f);
        float4_t b0 = *(const float4_t*)(bias + COL0 + flane * 8);
        float4_t b1 = *(const float4_t*)(bias + COL0 + flane * 8 + 4);
        half8_t o;
        o[0] = (_Float16)fmaxf(acc[0] * dv + b0[0], 0.0f);
        o[1] = (_Float16)fmaxf(acc[1] * dv + b0[1], 0.0f);
        o[2] = (_Float16)fmaxf(acc[2] * dv + b0[2], 0.0f);
        o[3] = (_Float16)fmaxf(acc[3] * dv + b0[3], 0.0f);
        o[4] = (_Float16)fmaxf(acc[4] * dv + b1[0], 0.0f);
        o[5] = (_Float16)fmaxf(acc[5] * dv + b1[1], 0.0f);
        o[6] = (_Float16)fmaxf(acc[6] * dv + b1[2], 0.0f);
        o[7] = (_Float16)fmaxf(acc[7] * dv + b1[3], 0.0f);
        *(half8_t*)(out + (size_t)node * 128 + COL0 + flane * 8) = o;
    }
}

// F=64 agg: one wave/node, 8 edges/iter. Epilogue: *dinv, +bias, fp32 out.
__global__ __launch_bounds__(256) void k_agg64(const int* __restrict__ cnt,
                                               const unsigned short* __restrict__ esrc_pad,
                                               const _Float16* __restrict__ g,
                                               const float* __restrict__ bias,
                                               float* __restrict__ out) {
    const int wave = threadIdx.x >> 6;
    const int lane = threadIdx.x & 63;
    const int node = blockIdx.x * 4 + wave;
    if (node >= N_NODES) return;
    const int eidx = lane >> 3;
    const int flane = lane & 7;

    const int end = cnt[node];
    const int base = node * STRIDE;

    float acc[8];
#pragma unroll
    for (int p = 0; p < 8; ++p) acc[p] = 0.0f;
    if (lane < 8) {
        half8_t s = *(const half8_t*)(g + (size_t)node * 64 + flane * 8);
#pragma unroll
        for (int p = 0; p < 8; ++p) acc[p] = (float)s[p];
    }

    int j = 0;
    for (; j + 7 < end; j += 8) {
        int s = (int)esrc_pad[base + j + eidx];
        half8_t r = *(const half8_t*)(g + (size_t)s * 64 + flane * 8);
#pragma unroll
        for (int p = 0; p < 8; ++p) acc[p] += (float)r[p];
    }
    if (j < end) {
        int idx = j + eidx;
        int s = (int)esrc_pad[base + ((idx < end) ? idx : (end - 1))];
        float valid = (idx < end) ? 1.0f : 0.0f;
        half8_t r = *(const half8_t*)(g + (size_t)s * 64 + flane * 8);
#pragma unroll
        for (int p = 0; p < 8; ++p) acc[p] += valid * (float)r[p];
    }

#pragma unroll
    for (int p = 0; p < 8; ++p) {
        acc[p] += __shfl_xor(acc[p], 32, 64);
        acc[p] += __shfl_xor(acc[p], 16, 64);
        acc[p] += __shfl_xor(acc[p], 8, 64);
    }

    if (lane < 8) {
        float dv = rsqrtf((float)end + 1.0f);
        float4_t b0 = *(const float4_t*)(bias + flane * 8);
        float4_t b1 = *(const float4_t*)(bias + flane * 8 + 4);
        float4_t o0, o1;
        o0[0] = acc[0] * dv + b0[0]; o0[1] = acc[1] * dv + b0[1];
        o0[2] = acc[2] * dv + b0[2]; o0[3] = acc[3] * dv + b0[3];
        o1[0] = acc[4] * dv + b1[0]; o1[1] = acc[5] * dv + b1[1];
        o1[2] = acc[6] * dv + b1[2]; o1[3] = acc[7] * dv + b1[3];
        *(float4_t*)(out + (size_t)node * 64 + flane * 8) = o0;
        *(float4_t*)(out + (size_t)node * 64 + flane * 8 + 4) = o1;
    }
}

extern "C" void kernel_launch(void* const* d_in, const int* in_sizes, int n_in,
                              void* d_out, int out_size, void* d_ws, size_t ws_size,
                              hipStream_t stream) {
    const float* x  = (const float*)d_in[0];
    const int*   ei = (const int*)d_in[1];
    const float* W1 = (const float*)d_in[2];
    const float* b1 = (const float*)d_in[3];
    const float* W2 = (const float*)d_in[4];
    const float* b2 = (const float*)d_in[5];

    const int* src = ei;
    const int* dst = ei + N_EDGES;

    char* w = (char*)d_ws;
    unsigned short* esrc_pad = (unsigned short*)w; w += sizeof(unsigned short) * (size_t)N_NODES * STRIDE;
    unsigned char*  ghist    = (unsigned char*)w;  w += (size_t)HB * N_NODES;
    unsigned char*  boff     = (unsigned char*)w;  w += (size_t)HB * N_NODES;
    _Float16*       g1a      = (_Float16*)w;       w += sizeof(_Float16) * (size_t)N_NODES * 64;
    _Float16*       g1b      = (_Float16*)w;       w += sizeof(_Float16) * (size_t)N_NODES * 64;
    _Float16*       h1p      = (_Float16*)w;       w += sizeof(_Float16) * (size_t)N_NODES * HID_DIM;
    _Float16*       g2       = (_Float16*)w;       w += sizeof(_Float16) * (size_t)N_NODES * OUT_DIM;
    _Float16*       WT1      = (_Float16*)w;       w += sizeof(_Float16) * 128 * 128;
    _Float16*       WT2      = (_Float16*)w;       w += sizeof(_Float16) * 64 * 128;
    int*            cnt      = (int*)w;            w += sizeof(int) * N_NODES;
    float*          out      = (float*)d_out;

    // No-atomic CSR build (+WT in p1, +gemm1 in p3)
    k_p1<<<HB + WT_NB, 256, 0, stream>>>(dst, ghist, W1, W2, WT1, WT2);
    k_p2<<<(N_NODES + 255) / 256, 256, 0, stream>>>(ghist, boff, cnt);
    k_p3<<<HB + GEMM1_NB, 256, 0, stream>>>(src, dst, boff, esrc_pad, x, WT1, cnt, g1a, g1b);

    // Layer 1 aggregation
    k_agg128h<0><<<(N_NODES + 3) / 4, 256, 0, stream>>>(cnt, esrc_pad, g1a, b1, h1p);
    k_agg128h<64><<<(N_NODES + 3) / 4, 256, 0, stream>>>(cnt, esrc_pad, g1b, b1, h1p);

    // Layer 2
    k_mgemm2<<<(2 * (N_NODES / 16) + 3) / 4, 256, 0, stream>>>(h1p, WT2, cnt, g2);
    k_agg64<<<(N_NODES + 3) / 4, 256, 0, stream>>>(cnt, esrc_pad, g2, b2, out);
}